// Round 3
// baseline (404.207 us; speedup 1.0000x reference)
//
#include <hip/hip_runtime.h>
#include <cstdint>
#include <cstddef>

// CausalSelfAttention on MI355X (gfx950). I/O tensors fp32 (per reference);
// compute in bf16 MFMA with fp32 accumulation; intermediates (qkv, y) bf16.
// B=2, T=2048, C=1024, H=16, Dh=64.
// Pipeline: [gemm qkv: f32->bf16] -> [rmsnorm+rope in-place bf16]
//           -> [flash attention bf16] -> [gemm proj: bf16 x f32 -> f32 out]

typedef short bf16x8 __attribute__((ext_vector_type(8)));   // 8 bf16 in 4 VGPRs
typedef float floatx4 __attribute__((ext_vector_type(4)));
typedef unsigned short ushortx8 __attribute__((ext_vector_type(8)));

#define DEVI __device__ __forceinline__

DEVI float bf2f(unsigned short u) {
    unsigned int x = ((unsigned int)u) << 16;
    return __builtin_bit_cast(float, x);
}
DEVI unsigned short f2bf(float f) {
    unsigned int u = __builtin_bit_cast(unsigned int, f);
    u += 0x7fffu + ((u >> 16) & 1u);   // RNE; finite inputs
    return (unsigned short)(u >> 16);
}
// exp with arg clamped (arg <= 0 by construction); exp(-80) = 1.8e-35 ~ 0.
DEVI float exp_nn(float x) { return expf(fmaxf(x, -80.0f)); }

// --- staging loaders: 8 contiguous source elems -> 8 bf16 in LDS (16B store)
DEVI void stage8(unsigned short* dst, const float* src) {
    floatx4 a = *(const floatx4*)src;
    floatx4 b = *(const floatx4*)(src + 4);
    ushortx8 o;
    o[0] = f2bf(a[0]); o[1] = f2bf(a[1]); o[2] = f2bf(a[2]); o[3] = f2bf(a[3]);
    o[4] = f2bf(b[0]); o[5] = f2bf(b[1]); o[6] = f2bf(b[2]); o[7] = f2bf(b[3]);
    *(ushortx8*)dst = o;
}
DEVI void stage8(unsigned short* dst, const unsigned short* src) {
    *(ushortx8*)dst = *(const ushortx8*)src;
}
DEVI void store_c(float* C, size_t idx, float v)          { C[idx] = v; }
DEVI void store_c(unsigned short* C, size_t idx, float v) { C[idx] = f2bf(v); }

// ---------------------------------------------------------------------------
// C[M,N] = A[M,K] @ B[N,K]^T   (both K-contiguous). TA/TB in {float, ushort},
// TC in {float, ushort}. 128x128 tile, BK=32, 4 waves 2x2, 4x4 mfma/wave.
// ---------------------------------------------------------------------------
template <typename TA, typename TB, typename TC>
__global__ __launch_bounds__(256)
void gemm_bt(const TA* __restrict__ A, const TB* __restrict__ B,
             TC* __restrict__ C, int M, int N, int K)
{
    constexpr int BM = 128, BN = 128, BK = 32;
    constexpr int LDT = BK + 8;  // 40: 16B row alignment, breaks pow2 bank stride
    __shared__ __align__(16) unsigned short As[BM * LDT];
    __shared__ __align__(16) unsigned short Bs[BN * LDT];

    const int tid  = threadIdx.x;
    const int lane = tid & 63;
    const int wid  = tid >> 6;
    const int wm   = wid >> 1, wn = wid & 1;
    const int quad = lane >> 4;
    const int lm   = lane & 15;

    const int m0 = blockIdx.y * BM;
    const int n0 = blockIdx.x * BN;

    floatx4 acc[4][4] = {};

    for (int k0 = 0; k0 < K; k0 += BK) {
        __syncthreads();
        #pragma unroll
        for (int i = 0; i < 2; ++i) {
            int c   = i * 256 + tid;     // 0..511
            int row = c >> 2;            // 0..127 (4 chunks of 8 per 32-col row)
            int col = (c & 3) * 8;       // 0,8,16,24
            stage8(&As[row * LDT + col], &A[(size_t)(m0 + row) * K + k0 + col]);
            stage8(&Bs[row * LDT + col], &B[(size_t)(n0 + row) * K + k0 + col]);
        }
        __syncthreads();

        bf16x8 a[4];
        #pragma unroll
        for (int i = 0; i < 4; ++i)
            a[i] = *(const bf16x8*)&As[(wm * 64 + i * 16 + lm) * LDT + quad * 8];
        #pragma unroll
        for (int j = 0; j < 4; ++j) {
            bf16x8 b = *(const bf16x8*)&Bs[(wn * 64 + j * 16 + lm) * LDT + quad * 8];
            #pragma unroll
            for (int i = 0; i < 4; ++i)
                acc[i][j] = __builtin_amdgcn_mfma_f32_16x16x32_bf16(a[i], b, acc[i][j], 0, 0, 0);
        }
    }

    // C/D layout: col = lane&15, row = quad*4 + reg  (m89-verified)
    #pragma unroll
    for (int i = 0; i < 4; ++i) {
        #pragma unroll
        for (int j = 0; j < 4; ++j) {
            int col = n0 + wn * 64 + j * 16 + lm;
            #pragma unroll
            for (int r = 0; r < 4; ++r) {
                int row = m0 + wm * 64 + i * 16 + quad * 4 + r;
                store_c(C, (size_t)row * N + col, acc[i][j][r]);
            }
        }
    }
}

// ---------------------------------------------------------------------------
// RMSNorm (over Dh=64, eps = fp32 eps) + rotary, IN PLACE on q,k thirds of
// qkv [B,T,3C] (bf16). One wave per (b,t,h); lane = d.
// ---------------------------------------------------------------------------
__global__ __launch_bounds__(256)
void rmsnorm_rope(unsigned short* __restrict__ qkv)
{
    int gw   = (blockIdx.x * 256 + threadIdx.x) >> 6;  // b*32768 + t*16 + h
    int lane = threadIdx.x & 63;
    int h = gw & 15;
    int t = (gw >> 4) & 2047;
    int b = gw >> 15;

    size_t base = ((size_t)(b * 2048 + t)) * 3072 + h * 64 + lane;
    float q = bf2f(qkv[base]);
    float k = bf2f(qkv[base + 1024]);

    float sq = q * q, sk = k * k;
    #pragma unroll
    for (int off = 32; off >= 1; off >>= 1) {
        sq += __shfl_xor(sq, off, 64);
        sk += __shfl_xor(sk, off, 64);
    }
    const float eps = 1.1920929e-07f;
    q *= rsqrtf(sq * (1.0f / 64.0f) + eps);
    k *= rsqrtf(sk * (1.0f / 64.0f) + eps);

    // inv_freq = 10000^(-(d%32)/32)
    int i = lane & 31;
    float ang = (float)t * expf(-(float)i * 0.28782313662425572f);
    float c = cosf(ang), s = sinf(ang);
    float qp = __shfl_xor(q, 32, 64);
    float kp = __shfl_xor(k, 32, 64);
    float sgn = (lane < 32) ? -1.0f : 1.0f;  // rotate_half: (-x2, x1)
    float qo = q * c + sgn * qp * s;
    float ko = k * c + sgn * kp * s;

    qkv[base]        = f2bf(qo);
    qkv[base + 1024] = f2bf(ko);
}

// ---------------------------------------------------------------------------
// Flash-style causal attention, q/k/v from bf16 qkv [B,T,3C]. Block = 4 waves;
// one (b,h) x 64-row Q tile. Per 64-key tile: QK^T (mfma) -> online softmax
// (quad shuffles) -> P via LDS (C-layout -> A-layout) -> PV (mfma, V^T in LDS).
// ---------------------------------------------------------------------------
__global__ __launch_bounds__(256)
void attention(const unsigned short* __restrict__ qkv,
               unsigned short* __restrict__ Y)
{
    constexpr int LD = 72;  // 64 + 8 pad
    __shared__ __align__(16) unsigned short Qs[64 * LD];
    __shared__ __align__(16) unsigned short Ks[64 * LD];
    __shared__ __align__(16) unsigned short Vt[64 * LD];
    __shared__ __align__(16) unsigned short Ps[64 * LD];

    const int tid  = threadIdx.x;
    const int lane = tid & 63;
    const int w    = tid >> 6;
    const int quad = lane >> 4;
    const int lm   = lane & 15;

    const int qt = blockIdx.x;           // q tile (32)
    const int bh = blockIdx.y;           // b*16+h (32)
    const int b  = bh >> 4, h = bh & 15;
    const int q0 = qt * 64;

    // stage Q tile once (rows stride 3072 in qkv)
    #pragma unroll
    for (int i = 0; i < 2; ++i) {
        int c = i * 256 + tid;
        int row = c >> 3;
        int col = (c & 7) * 8;
        *(ushortx8*)&Qs[row * LD + col] =
            *(const ushortx8*)&qkv[((size_t)(b * 2048 + q0 + row)) * 3072 + h * 64 + col];
    }

    floatx4 o[4] = {};
    float m_i[4], l_i[4];
    const float MNEG = -30000.0f;
    #pragma unroll
    for (int r = 0; r < 4; ++r) { m_i[r] = MNEG; l_i[r] = 0.0f; }
    const float scale = 0.125f;          // 1/sqrt(64)

    for (int kt = 0; kt <= qt; ++kt) {
        const int k0 = kt * 64;
        __syncthreads();  // prev compute done (covers Q stage on iter 0)
        #pragma unroll
        for (int i = 0; i < 2; ++i) {
            int c = i * 256 + tid;
            int row = c >> 3;           // key index
            int col = (c & 7) * 8;      // d0
            size_t rb = ((size_t)(b * 2048 + k0 + row)) * 3072 + h * 64 + col;
            *(ushortx8*)&Ks[row * LD + col] = *(const ushortx8*)&qkv[rb + 1024];
            ushortx8 v8 = *(const ushortx8*)&qkv[rb + 2048];
            #pragma unroll
            for (int jj = 0; jj < 8; ++jj)
                Vt[(col + jj) * LD + row] = v8[jj];  // transpose: Vt[d][key]
        }
        __syncthreads();

        // S strip 16x64: A = Q rows, B = K rows (both k-major)
        floatx4 sa[4] = {};
        #pragma unroll
        for (int kk = 0; kk < 2; ++kk) {
            bf16x8 af = *(const bf16x8*)&Qs[(w * 16 + lm) * LD + kk * 32 + quad * 8];
            #pragma unroll
            for (int j = 0; j < 4; ++j) {
                bf16x8 bfr = *(const bf16x8*)&Ks[(j * 16 + lm) * LD + kk * 32 + quad * 8];
                sa[j] = __builtin_amdgcn_mfma_f32_16x16x32_bf16(af, bfr, sa[j], 0, 0, 0);
            }
        }

        float p[4][4];
        const bool diag = (kt == qt);
        #pragma unroll
        for (int j = 0; j < 4; ++j) {
            int colg = k0 + j * 16 + lm;
            #pragma unroll
            for (int r = 0; r < 4; ++r) {
                float s = sa[j][r] * scale;
                if (diag) {
                    int rowg = q0 + w * 16 + quad * 4 + r;
                    if (colg > rowg) s = MNEG;
                }
                p[j][r] = s;
            }
        }

        // online softmax per row (row = 16 lanes of one quad)
        #pragma unroll
        for (int r = 0; r < 4; ++r) {
            float mj = fmaxf(fmaxf(p[0][r], p[1][r]), fmaxf(p[2][r], p[3][r]));
            #pragma unroll
            for (int off = 1; off <= 8; off <<= 1)
                mj = fmaxf(mj, __shfl_xor(mj, off, 64));
            float mn = fmaxf(m_i[r], mj);
            float al = exp_nn(m_i[r] - mn);
            float ps = 0.0f;
            #pragma unroll
            for (int j = 0; j < 4; ++j) {
                p[j][r] = exp_nn(p[j][r] - mn);
                ps += p[j][r];
            }
            #pragma unroll
            for (int off = 1; off <= 8; off <<= 1)
                ps += __shfl_xor(ps, off, 64);
            l_i[r] = al * l_i[r] + ps;
            m_i[r] = mn;
            #pragma unroll
            for (int j = 0; j < 4; ++j)
                o[j][r] *= al;
        }

        // P: C-layout regs -> LDS -> A-layout frags
        #pragma unroll
        for (int j = 0; j < 4; ++j)
            #pragma unroll
            for (int r = 0; r < 4; ++r)
                Ps[(w * 16 + quad * 4 + r) * LD + j * 16 + lm] = f2bf(p[j][r]);
        __syncthreads();

        #pragma unroll
        for (int kk = 0; kk < 2; ++kk) {
            bf16x8 af = *(const bf16x8*)&Ps[(w * 16 + lm) * LD + kk * 32 + quad * 8];
            #pragma unroll
            for (int j = 0; j < 4; ++j) {
                bf16x8 bfr = *(const bf16x8*)&Vt[(j * 16 + lm) * LD + kk * 32 + quad * 8];
                o[j] = __builtin_amdgcn_mfma_f32_16x16x32_bf16(af, bfr, o[j], 0, 0, 0);
            }
        }
    }

    // epilogue: y[b, t, h*64 + d] (bf16 intermediate)
    #pragma unroll
    for (int j = 0; j < 4; ++j) {
        int colg = h * 64 + j * 16 + lm;
        #pragma unroll
        for (int r = 0; r < 4; ++r) {
            int rowg = q0 + w * 16 + quad * 4 + r;
            float val = o[j][r] / l_i[r];   // l_i >= ~1 (diagonal always present)
            Y[((size_t)(b * 2048 + rowg)) * 1024 + colg] = f2bf(val);
        }
    }
}

// ---------------------------------------------------------------------------
extern "C" void kernel_launch(void* const* d_in, const int* in_sizes, int n_in,
                              void* d_out, int out_size, void* d_ws, size_t ws_size,
                              hipStream_t stream)
{
    const float* x      = (const float*)d_in[0];   // [2,2048,1024] fp32
    const float* w_attn = (const float*)d_in[1];   // [3072,1024] fp32
    const float* w_proj = (const float*)d_in[2];   // [1024,1024] fp32
    float* out = (float*)d_out;                    // [2,2048,1024] fp32

    unsigned short* qkv = (unsigned short*)d_ws;       // 4096*3072 bf16 (25.2 MB)
    unsigned short* y   = qkv + (size_t)4096 * 3072;   // 4096*1024  bf16 (8.4 MB)

    dim3 blk(256);
    // qkv = x @ w_attn^T : M=4096, N=3072, K=1024 (f32 in, bf16 out)
    gemm_bt<float, float, unsigned short>
        <<<dim3(24, 32), blk, 0, stream>>>(x, w_attn, qkv, 4096, 3072, 1024);
    // q,k -> rmsnorm -> rope, in place
    rmsnorm_rope<<<dim3(16384), blk, 0, stream>>>(qkv);
    // causal flash attention -> y
    attention<<<dim3(32, 32), blk, 0, stream>>>(qkv, y);
    // out = y @ w_proj^T : M=4096, N=1024, K=1024 (bf16 x f32 -> f32 out)
    gemm_bt<unsigned short, float, float>
        <<<dim3(8, 32), blk, 0, stream>>>(y, w_proj, out, 4096, 1024, 1024);
}

// Round 4
// 226.433 us; speedup vs baseline: 1.7851x; 1.7851x over previous
//
#include <hip/hip_runtime.h>
#include <cstdint>
#include <cstddef>

// CausalSelfAttention MI355X (gfx950). fp32 I/O, bf16 MFMA compute, fp32 accum.
// B=2, T=2048, C=1024, H=16, Dh=64.
// [cast f32->bf16 (into d_out scratch)] -> [gemm qkv, V-third stored transposed]
// -> [rmsnorm+rope in-place] -> [flash attention, static-max softmax] -> [gemm proj -> f32 out]

typedef short bf16x8 __attribute__((ext_vector_type(8)));
typedef float floatx4 __attribute__((ext_vector_type(4)));
typedef unsigned short ushortx8 __attribute__((ext_vector_type(8)));

#define DEVI __device__ __forceinline__

DEVI float bf2f(unsigned short u) {
    unsigned int x = ((unsigned int)u) << 16;
    return __builtin_bit_cast(float, x);
}
DEVI unsigned short f2bf(float f) {
    unsigned int u = __builtin_bit_cast(unsigned int, f);
    u += 0x7fffu + ((u >> 16) & 1u);   // RNE; finite values only
    return (unsigned short)(u >> 16);
}

// 8 contiguous source elems -> 8 bf16 (16B store). Overloads: f32 converts, bf16 copies.
DEVI void stage8(unsigned short* dst, const float* src) {
    floatx4 a = *(const floatx4*)src;
    floatx4 b = *(const floatx4*)(src + 4);
    ushortx8 o;
    o[0] = f2bf(a[0]); o[1] = f2bf(a[1]); o[2] = f2bf(a[2]); o[3] = f2bf(a[3]);
    o[4] = f2bf(b[0]); o[5] = f2bf(b[1]); o[6] = f2bf(b[2]); o[7] = f2bf(b[3]);
    *(ushortx8*)dst = o;
}
DEVI void stage8(unsigned short* dst, const unsigned short* src) {
    *(ushortx8*)dst = *(const ushortx8*)src;
}

// ---------------------------------------------------------------------------
// Pre-cast x and w_attn to bf16 (targets live in d_out scratch).
// ---------------------------------------------------------------------------
__global__ __launch_bounds__(256)
void cast_inputs(const float* __restrict__ x, const float* __restrict__ wa,
                 unsigned short* __restrict__ xb, unsigned short* __restrict__ wab)
{
    size_t g = (size_t)blockIdx.x * 256 + threadIdx.x;
    size_t stride = (size_t)gridDim.x * 256;
    for (size_t i = g; i < (4194304 / 8); i += stride) stage8(xb  + i * 8, x  + i * 8);
    for (size_t i = g; i < (3145728 / 8); i += stride) stage8(wab + i * 8, wa + i * 8);
}

// ---------------------------------------------------------------------------
// C[M,N] = A[M,K] @ B[N,K]^T (bf16 LDS, fp32 accum). 128x128 tile, BK=32.
// QKV_SPLIT: cols<2048 -> qk[row*2048+col] bf16; cols>=2048 -> Vt[bh*64+d][t] bf16.
// else: Cf[row*N+col] = fp32.
// ---------------------------------------------------------------------------
template <typename TA, typename TB, bool QKV_SPLIT>
__global__ __launch_bounds__(256)
void gemm_bt(const TA* __restrict__ A, const TB* __restrict__ B,
             unsigned short* __restrict__ Cus, float* __restrict__ Cf,
             unsigned short* __restrict__ Vt, int M, int N, int K)
{
    constexpr int BM = 128, BN = 128, BK = 32;
    constexpr int LDT = BK + 8;  // 40
    __shared__ __align__(16) unsigned short As[BM * LDT];
    __shared__ __align__(16) unsigned short Bs[BN * LDT];

    const int tid  = threadIdx.x;
    const int lane = tid & 63;
    const int wid  = tid >> 6;
    const int wm   = wid >> 1, wn = wid & 1;
    const int quad = lane >> 4;
    const int lm   = lane & 15;

    const int m0 = blockIdx.y * BM;
    const int n0 = blockIdx.x * BN;

    floatx4 acc[4][4] = {};

    for (int k0 = 0; k0 < K; k0 += BK) {
        __syncthreads();
        #pragma unroll
        for (int i = 0; i < 2; ++i) {
            int c   = i * 256 + tid;
            int row = c >> 2;
            int col = (c & 3) * 8;
            stage8(&As[row * LDT + col], &A[(size_t)(m0 + row) * K + k0 + col]);
            stage8(&Bs[row * LDT + col], &B[(size_t)(n0 + row) * K + k0 + col]);
        }
        __syncthreads();

        bf16x8 a[4];
        #pragma unroll
        for (int i = 0; i < 4; ++i)
            a[i] = *(const bf16x8*)&As[(wm * 64 + i * 16 + lm) * LDT + quad * 8];
        #pragma unroll
        for (int j = 0; j < 4; ++j) {
            bf16x8 b = *(const bf16x8*)&Bs[(wn * 64 + j * 16 + lm) * LDT + quad * 8];
            #pragma unroll
            for (int i = 0; i < 4; ++i)
                acc[i][j] = __builtin_amdgcn_mfma_f32_16x16x32_bf16(a[i], b, acc[i][j], 0, 0, 0);
        }
    }

    // C/D layout: col = lane&15, row = quad*4 + reg
    #pragma unroll
    for (int i = 0; i < 4; ++i) {
        #pragma unroll
        for (int j = 0; j < 4; ++j) {
            int col = n0 + wn * 64 + j * 16 + lm;
            #pragma unroll
            for (int r = 0; r < 4; ++r) {
                int row = m0 + wm * 64 + i * 16 + quad * 4 + r;
                if constexpr (QKV_SPLIT) {
                    unsigned short v = f2bf(acc[i][j][r]);
                    if (col < 2048) {
                        Cus[(size_t)row * 2048 + col] = v;           // q,k thirds
                    } else {
                        // V: transpose at the source -> Vt[(b*16+h)*64+d][t]
                        int bq = row >> 11, t = row & 2047;
                        Vt[((size_t)(bq * 1024 + (col - 2048))) * 2048 + t] = v;
                    }
                } else {
                    Cf[(size_t)row * N + col] = acc[i][j][r];
                }
            }
        }
    }
}

// ---------------------------------------------------------------------------
// RMSNorm (Dh=64, eps=f32 eps) + rotary, IN PLACE on qk [B,T,2C] bf16.
// One wave per (b,t,h); lane = d.
// ---------------------------------------------------------------------------
__global__ __launch_bounds__(256)
void rmsnorm_rope(unsigned short* __restrict__ qk)
{
    int gw   = (blockIdx.x * 256 + threadIdx.x) >> 6;
    int lane = threadIdx.x & 63;
    int h = gw & 15;
    int t = (gw >> 4) & 2047;
    int b = gw >> 15;

    size_t base = ((size_t)(b * 2048 + t)) * 2048 + h * 64 + lane;
    float q = bf2f(qk[base]);
    float k = bf2f(qk[base + 1024]);

    float sq = q * q, sk = k * k;
    #pragma unroll
    for (int off = 32; off >= 1; off >>= 1) {
        sq += __shfl_xor(sq, off, 64);
        sk += __shfl_xor(sk, off, 64);
    }
    const float eps = 1.1920929e-07f;
    q *= rsqrtf(sq * (1.0f / 64.0f) + eps);
    k *= rsqrtf(sk * (1.0f / 64.0f) + eps);

    int i = lane & 31;
    float ang = (float)t * expf(-(float)i * 0.28782313662425572f);  // ln(1e4)/32
    float c = cosf(ang), s = sinf(ang);
    float qp = __shfl_xor(q, 32, 64);
    float kp = __shfl_xor(k, 32, 64);
    float sgn = (lane < 32) ? -1.0f : 1.0f;
    float qo = q * c + sgn * qp * s;
    float ko = k * c + sgn * kp * s;

    qk[base]        = f2bf(qo);
    qk[base + 1024] = f2bf(ko);
}

// ---------------------------------------------------------------------------
// Flash attention, static-max softmax. RMSNorm => |s| <= 8, so p = exp(s-8)
// with NO running max / rescale; masked entries exactly 0; l accumulated
// per-lane, one cross-lane reduce at the end. K/V prefetched to regs (double
// buffer); V comes pre-transposed (Vt[bh*64+d][t]); Q frags hoisted once and
// Ps reuses the Q LDS array. 2 barriers/step. 27.6 KB LDS -> 5 blocks/CU.
// ---------------------------------------------------------------------------
__global__ __launch_bounds__(256)
void attention(const unsigned short* __restrict__ qk,
               const unsigned short* __restrict__ Vt,
               unsigned short* __restrict__ Y)
{
    constexpr int LD = 72;
    __shared__ __align__(16) unsigned short QPs[64 * LD];  // Q stage, then P
    __shared__ __align__(16) unsigned short Ks [64 * LD];
    __shared__ __align__(16) unsigned short Vs [64 * LD];  // rows=d, cols=key

    const int tid  = threadIdx.x;
    const int lane = tid & 63;
    const int w    = tid >> 6;
    const int quad = lane >> 4;
    const int lm   = lane & 15;

    const int bh = blockIdx.x;            // b*16+h
    const int qt = 31 - blockIdx.y;       // longest blocks dispatch first
    const int b  = bh >> 4, h = bh & 15;
    const int q0 = qt * 64;

    // stage Q tile
    #pragma unroll
    for (int i = 0; i < 2; ++i) {
        int c = i * 256 + tid, row = c >> 3, col = (c & 7) * 8;
        *(ushortx8*)&QPs[row * LD + col] =
            *(const ushortx8*)&qk[((size_t)(b * 2048 + q0 + row)) * 2048 + h * 64 + col];
    }

    // prefetch tile 0 into regs
    ushortx8 kreg[2], vreg[2];
    #pragma unroll
    for (int i = 0; i < 2; ++i) {
        int c = i * 256 + tid, row = c >> 3, col = (c & 7) * 8;
        kreg[i] = *(const ushortx8*)&qk[((size_t)(b * 2048 + row)) * 2048 + 1024 + h * 64 + col];
        vreg[i] = *(const ushortx8*)&Vt[((size_t)(bh * 64 + row)) * 2048 + col];
    }

    floatx4 o[4] = {};
    float lsum[4] = {0.f, 0.f, 0.f, 0.f};
    bf16x8 af[2];
    const float c1 = 0.125f * 1.44269504f;   // scale * log2(e)
    const float c2 = 8.0f   * 1.44269504f;   // static max 8 (|s|<=8 from RMSNorm)

    for (int kt = 0; kt <= qt; ++kt) {
        const int k0 = kt * 64;
        __syncthreads();                     // all waves done with prev tile LDS
        #pragma unroll
        for (int i = 0; i < 2; ++i) {
            int c = i * 256 + tid, row = c >> 3, col = (c & 7) * 8;
            *(ushortx8*)&Ks[row * LD + col] = kreg[i];
            *(ushortx8*)&Vs[row * LD + col] = vreg[i];
        }
        __syncthreads();                     // tile visible

        if (kt == 0) {                       // hoist Q frags (valid all steps)
            #pragma unroll
            for (int kk = 0; kk < 2; ++kk)
                af[kk] = *(const bf16x8*)&QPs[(w * 16 + lm) * LD + kk * 32 + quad * 8];
        }
        if (kt < qt) {                       // prefetch next tile during compute
            const int kn = k0 + 64;
            #pragma unroll
            for (int i = 0; i < 2; ++i) {
                int c = i * 256 + tid, row = c >> 3, col = (c & 7) * 8;
                kreg[i] = *(const ushortx8*)&qk[((size_t)(b * 2048 + kn + row)) * 2048 + 1024 + h * 64 + col];
                vreg[i] = *(const ushortx8*)&Vt[((size_t)(bh * 64 + row)) * 2048 + kn + col];
            }
        }

        // S = Q K^T (16x64 strip per wave)
        floatx4 sa[4] = {};
        #pragma unroll
        for (int kk = 0; kk < 2; ++kk) {
            #pragma unroll
            for (int j = 0; j < 4; ++j) {
                bf16x8 bfr = *(const bf16x8*)&Ks[(j * 16 + lm) * LD + kk * 32 + quad * 8];
                sa[j] = __builtin_amdgcn_mfma_f32_16x16x32_bf16(af[kk], bfr, sa[j], 0, 0, 0);
            }
        }

        // p = exp(s*scale - 8); masked -> 0. No shuffles, no rescale.
        const bool dg = (kt == qt);
        const int rbase = q0 + w * 16 + quad * 4;
        #pragma unroll
        for (int j = 0; j < 4; ++j) {
            int colg = k0 + j * 16 + lm;
            #pragma unroll
            for (int r = 0; r < 4; ++r) {
                float p = exp2f(sa[j][r] * c1 - c2);
                if (dg && colg > rbase + r) p = 0.0f;
                lsum[r] += p;
                QPs[(w * 16 + quad * 4 + r) * LD + j * 16 + lm] = f2bf(p);  // own strip
            }
        }

        // O += P V  (P round-trip is same-wave; lgkmcnt orders it)
        #pragma unroll
        for (int kk = 0; kk < 2; ++kk) {
            bf16x8 pf = *(const bf16x8*)&QPs[(w * 16 + lm) * LD + kk * 32 + quad * 8];
            #pragma unroll
            for (int j = 0; j < 4; ++j) {
                bf16x8 bfr = *(const bf16x8*)&Vs[(j * 16 + lm) * LD + kk * 32 + quad * 8];
                o[j] = __builtin_amdgcn_mfma_f32_16x16x32_bf16(pf, bfr, o[j], 0, 0, 0);
            }
        }
    }

    // single end-of-kernel row-sum reduction (16 lanes of each quad = one row)
    float rinv[4];
    #pragma unroll
    for (int r = 0; r < 4; ++r) {
        float l = lsum[r];
        l += __shfl_xor(l, 1, 64);
        l += __shfl_xor(l, 2, 64);
        l += __shfl_xor(l, 4, 64);
        l += __shfl_xor(l, 8, 64);
        rinv[r] = 1.0f / l;
    }
    #pragma unroll
    for (int j = 0; j < 4; ++j) {
        int colg = h * 64 + j * 16 + lm;
        #pragma unroll
        for (int r = 0; r < 4; ++r) {
            int rowg = q0 + w * 16 + quad * 4 + r;
            Y[((size_t)(b * 2048 + rowg)) * 1024 + colg] = f2bf(o[j][r] * rinv[r]);
        }
    }
}

// ---------------------------------------------------------------------------
extern "C" void kernel_launch(void* const* d_in, const int* in_sizes, int n_in,
                              void* d_out, int out_size, void* d_ws, size_t ws_size,
                              hipStream_t stream)
{
    const float* x      = (const float*)d_in[0];   // [2,2048,1024] fp32
    const float* w_attn = (const float*)d_in[1];   // [3072,1024] fp32
    const float* w_proj = (const float*)d_in[2];   // [1024,1024] fp32
    float* out = (float*)d_out;                    // [2,2048,1024] fp32

    // workspace (33.55 MB, same footprint as round 3):
    unsigned short* qkbuf = (unsigned short*)d_ws;            // [4096][2048] q|k bf16
    unsigned short* Vtb   = qkbuf + (size_t)4096 * 2048;      // [32*64][2048] V^T bf16
    unsigned short* y     = Vtb   + (size_t)32 * 64 * 2048;   // [4096][1024] bf16
    // d_out doubles as pre-cast scratch (dead before proj writes it):
    unsigned short* xb  = (unsigned short*)d_out;             // 4096*1024 bf16
    unsigned short* wab = xb + (size_t)4096 * 1024;           // 3072*1024 bf16

    dim3 blk(256);
    cast_inputs<<<dim3(1024), blk, 0, stream>>>(x, w_attn, xb, wab);
    // qkv GEMM: q,k -> qkbuf; V-third stored transposed into Vtb
    gemm_bt<unsigned short, unsigned short, true>
        <<<dim3(24, 32), blk, 0, stream>>>(xb, wab, qkbuf, nullptr, Vtb, 4096, 3072, 1024);
    rmsnorm_rope<<<dim3(16384), blk, 0, stream>>>(qkbuf);
    attention<<<dim3(32, 32), blk, 0, stream>>>(qkbuf, Vtb, y);
    // proj: bf16 A x f32-staged B -> f32 out (overwrites the cast scratch)
    gemm_bt<unsigned short, float, false>
        <<<dim3(8, 32), blk, 0, stream>>>(y, w_proj, nullptr, out, nullptr, 4096, 1024, 1024);
}

// Round 5
// 211.968 us; speedup vs baseline: 1.9069x; 1.0682x over previous
//
#include <hip/hip_runtime.h>
#include <cstdint>
#include <cstddef>

// CausalSelfAttention MI355X (gfx950). fp32 I/O, bf16 MFMA compute, fp32 accum.
// B=2, T=2048, C=1024, H=16, Dh=64.
// [cast f32->bf16] -> [gemm qkv (global_load_lds), V stored transposed]
// -> [rmsnorm+rope in-place] -> [flash attention, S^T + static-max softmax]
// -> [gemm proj (global_load_lds) -> f32 out]

typedef short bf16x8 __attribute__((ext_vector_type(8)));
typedef float floatx4 __attribute__((ext_vector_type(4)));
typedef unsigned short ushortx8 __attribute__((ext_vector_type(8)));
typedef unsigned short ushortx4 __attribute__((ext_vector_type(4)));

#define DEVI __device__ __forceinline__

DEVI float bf2f(unsigned short u) {
    unsigned int x = ((unsigned int)u) << 16;
    return __builtin_bit_cast(float, x);
}
DEVI unsigned short f2bf(float f) {
    unsigned int u = __builtin_bit_cast(unsigned int, f);
    u += 0x7fffu + ((u >> 16) & 1u);   // RNE; finite values only
    return (unsigned short)(u >> 16);
}

// async global->LDS, 16B per lane; LDS dest = wave-uniform base + lane*16.
DEVI void glds16(const unsigned short* g, unsigned short* l) {
    __builtin_amdgcn_global_load_lds(
        (const __attribute__((address_space(1))) unsigned int*)g,
        (__attribute__((address_space(3))) unsigned int*)l, 16, 0, 0);
}

DEVI void cast8(unsigned short* dst, const float* src) {
    floatx4 a = *(const floatx4*)src;
    floatx4 b = *(const floatx4*)(src + 4);
    ushortx8 o;
    o[0] = f2bf(a[0]); o[1] = f2bf(a[1]); o[2] = f2bf(a[2]); o[3] = f2bf(a[3]);
    o[4] = f2bf(b[0]); o[5] = f2bf(b[1]); o[6] = f2bf(b[2]); o[7] = f2bf(b[3]);
    *(ushortx8*)dst = o;
}

// ---------------------------------------------------------------------------
__global__ __launch_bounds__(256)
void cast_inputs(const float* __restrict__ x, const float* __restrict__ wa,
                 const float* __restrict__ wp,
                 unsigned short* __restrict__ xb, unsigned short* __restrict__ wab,
                 unsigned short* __restrict__ wpb)
{
    size_t g = (size_t)blockIdx.x * 256 + threadIdx.x;
    size_t stride = (size_t)gridDim.x * 256;
    for (size_t i = g; i < (4194304 / 8); i += stride) cast8(xb  + i * 8, x  + i * 8);
    for (size_t i = g; i < (3145728 / 8); i += stride) cast8(wab + i * 8, wa + i * 8);
    for (size_t i = g; i < (1048576 / 8); i += stride) cast8(wpb + i * 8, wp + i * 8);
}

// ---------------------------------------------------------------------------
// C[M,N] = A[M,K] @ B[N,K]^T, bf16 in, fp32 accum. m97 structure: 128x128
// tile, BK=32, global_load_lds width=16 into UNPADDED LDS (row = 64B).
// QKV_SPLIT: col<2048 -> Cqk[row*2048+col] bf16; col>=2048 -> Vt[bh*64+d][t].
// else: Cf[row*N+col] fp32.
// ---------------------------------------------------------------------------
template <bool QKV_SPLIT>
__global__ __launch_bounds__(256)
void gemm_bt(const unsigned short* __restrict__ A, const unsigned short* __restrict__ B,
             unsigned short* __restrict__ Cqk, float* __restrict__ Cf,
             unsigned short* __restrict__ Vt, int M, int N, int K)
{
    __shared__ __align__(16) unsigned short As[128 * 32];
    __shared__ __align__(16) unsigned short Bs[128 * 32];

    const int tid  = threadIdx.x;
    const int lane = tid & 63;
    const int w    = tid >> 6;
    const int wm   = w >> 1, wn = w & 1;
    const int quad = lane >> 4;
    const int lm   = lane & 15;
    const int m0 = blockIdx.y * 128;
    const int n0 = blockIdx.x * 128;
    const int sr = lane >> 2;          // staging row within 16-row group
    const int sc = (lane & 3) * 8;     // staging col (8 shorts = 16B)

    floatx4 acc[4][4] = {};

    for (int k0 = 0; k0 < K; k0 += 32) {
        __syncthreads();               // WAR: everyone done reading LDS
        #pragma unroll
        for (int i = 0; i < 2; ++i) {
            int r = w * 32 + i * 16;   // wave-uniform group base row
            glds16(&A[(size_t)(m0 + r + sr) * K + k0 + sc], &As[r * 32]);
            glds16(&B[(size_t)(n0 + r + sr) * K + k0 + sc], &Bs[r * 32]);
        }
        __syncthreads();               // vmcnt(0) drained before barrier

        bf16x8 a[4];
        #pragma unroll
        for (int i = 0; i < 4; ++i)
            a[i] = *(const bf16x8*)&As[(wm * 64 + i * 16 + lm) * 32 + quad * 8];
        #pragma unroll
        for (int j = 0; j < 4; ++j) {
            bf16x8 b = *(const bf16x8*)&Bs[(wn * 64 + j * 16 + lm) * 32 + quad * 8];
            #pragma unroll
            for (int i = 0; i < 4; ++i)
                acc[i][j] = __builtin_amdgcn_mfma_f32_16x16x32_bf16(a[i], b, acc[i][j], 0, 0, 0);
        }
    }

    // C/D layout: col = lane&15, row = quad*4 + reg
    #pragma unroll
    for (int i = 0; i < 4; ++i) {
        #pragma unroll
        for (int j = 0; j < 4; ++j) {
            int col = n0 + wn * 64 + j * 16 + lm;
            #pragma unroll
            for (int r = 0; r < 4; ++r) {
                int row = m0 + wm * 64 + i * 16 + quad * 4 + r;
                if constexpr (QKV_SPLIT) {
                    unsigned short v = f2bf(acc[i][j][r]);
                    if (col < 2048) {
                        Cqk[(size_t)row * 2048 + col] = v;           // q,k thirds
                    } else {
                        int bq = row >> 11, t = row & 2047;          // V -> Vt[bh*64+d][t]
                        Vt[((size_t)(bq * 1024 + (col - 2048))) * 2048 + t] = v;
                    }
                } else {
                    Cf[(size_t)row * N + col] = acc[i][j][r];
                }
            }
        }
    }
}

// ---------------------------------------------------------------------------
// RMSNorm (Dh=64, eps=f32 eps) + rotary, IN PLACE on qk [B,T,2C] bf16.
// ---------------------------------------------------------------------------
__global__ __launch_bounds__(256)
void rmsnorm_rope(unsigned short* __restrict__ qk)
{
    int gw   = (blockIdx.x * 256 + threadIdx.x) >> 6;
    int lane = threadIdx.x & 63;
    int h = gw & 15;
    int t = (gw >> 4) & 2047;
    int b = gw >> 15;

    size_t base = ((size_t)(b * 2048 + t)) * 2048 + h * 64 + lane;
    float q = bf2f(qk[base]);
    float k = bf2f(qk[base + 1024]);

    float sq = q * q, sk = k * k;
    #pragma unroll
    for (int off = 32; off >= 1; off >>= 1) {
        sq += __shfl_xor(sq, off, 64);
        sk += __shfl_xor(sk, off, 64);
    }
    const float eps = 1.1920929e-07f;
    q *= rsqrtf(sq * (1.0f / 64.0f) + eps);
    k *= rsqrtf(sk * (1.0f / 64.0f) + eps);

    int i = lane & 31;
    float ang = (float)t * expf(-(float)i * 0.28782313662425572f);  // ln(1e4)/32
    float c = cosf(ang), s = sinf(ang);
    float qp = __shfl_xor(q, 32, 64);
    float kp = __shfl_xor(k, 32, 64);
    float sgn = (lane < 32) ? -1.0f : 1.0f;
    float qo = q * c + sgn * qp * s;
    float ko = k * c + sgn * kp * s;

    qk[base]        = f2bf(qo);
    qk[base + 1024] = f2bf(ko);
}

// ---------------------------------------------------------------------------
// Flash attention, static-max softmax (RMSNorm => |s|<=8 => p=exp(s-8), no
// rescale, masked entries exactly 0). NEW: compute S^T via mfma(A=K, B=Q):
// lane holds one q-row (lm) and key-contiguous P values -> P round-trip is
// 4 packed ds_write_b64 (2-way conflicts = free) + 2 b128 reads. PV unchanged
// (A=P, B=V^T); O layout and epilogue identical to round 4.
// ---------------------------------------------------------------------------
__global__ __launch_bounds__(256)
void attention(const unsigned short* __restrict__ qk,
               const unsigned short* __restrict__ Vt,
               unsigned short* __restrict__ Y)
{
    constexpr int LD = 72;
    __shared__ __align__(16) unsigned short QPs[64 * LD];  // Q stage, then P
    __shared__ __align__(16) unsigned short Ks [64 * LD];
    __shared__ __align__(16) unsigned short Vs [64 * LD];  // rows=d, cols=key

    const int tid  = threadIdx.x;
    const int lane = tid & 63;
    const int w    = tid >> 6;
    const int quad = lane >> 4;
    const int lm   = lane & 15;

    const int bh = blockIdx.x;
    const int qt = 31 - blockIdx.y;      // longest first
    const int b  = bh >> 4, h = bh & 15;
    const int q0 = qt * 64;
    const int qrow = q0 + w * 16 + lm;   // this lane's q-row (S^T layout)

    #pragma unroll
    for (int i = 0; i < 2; ++i) {
        int c = i * 256 + tid, row = c >> 3, col = (c & 7) * 8;
        *(ushortx8*)&QPs[row * LD + col] =
            *(const ushortx8*)&qk[((size_t)(b * 2048 + q0 + row)) * 2048 + h * 64 + col];
    }

    ushortx8 kreg[2], vreg[2];
    #pragma unroll
    for (int i = 0; i < 2; ++i) {
        int c = i * 256 + tid, row = c >> 3, col = (c & 7) * 8;
        kreg[i] = *(const ushortx8*)&qk[((size_t)(b * 2048 + row)) * 2048 + 1024 + h * 64 + col];
        vreg[i] = *(const ushortx8*)&Vt[((size_t)(bh * 64 + row)) * 2048 + col];
    }

    floatx4 o[4] = {};
    float lsum = 0.0f;
    bf16x8 qf[2];
    const float c1 = 0.125f * 1.44269504f;   // scale * log2(e)
    const float c2 = 8.0f   * 1.44269504f;   // static max 8

    for (int kt = 0; kt <= qt; ++kt) {
        const int k0 = kt * 64;
        __syncthreads();
        #pragma unroll
        for (int i = 0; i < 2; ++i) {
            int c = i * 256 + tid, row = c >> 3, col = (c & 7) * 8;
            *(ushortx8*)&Ks[row * LD + col] = kreg[i];
            *(ushortx8*)&Vs[row * LD + col] = vreg[i];
        }
        __syncthreads();

        if (kt == 0) {
            #pragma unroll
            for (int kk = 0; kk < 2; ++kk)
                qf[kk] = *(const bf16x8*)&QPs[(w * 16 + lm) * LD + kk * 32 + quad * 8];
        }
        if (kt < qt) {
            const int kn = k0 + 64;
            #pragma unroll
            for (int i = 0; i < 2; ++i) {
                int c = i * 256 + tid, row = c >> 3, col = (c & 7) * 8;
                kreg[i] = *(const ushortx8*)&qk[((size_t)(b * 2048 + kn + row)) * 2048 + 1024 + h * 64 + col];
                vreg[i] = *(const ushortx8*)&Vt[((size_t)(bh * 64 + row)) * 2048 + kn + col];
            }
        }

        // S^T: D[m=key-in-strip][n=q] = K_strip . Q^T; sa[j][r]:
        // lane(quad,lm): q = qrow, key = k0 + j*16 + quad*4 + r
        floatx4 sa[4] = {};
        #pragma unroll
        for (int kk = 0; kk < 2; ++kk) {
            #pragma unroll
            for (int j = 0; j < 4; ++j) {
                bf16x8 kf = *(const bf16x8*)&Ks[(j * 16 + lm) * LD + kk * 32 + quad * 8];
                sa[j] = __builtin_amdgcn_mfma_f32_16x16x32_bf16(kf, qf[kk], sa[j], 0, 0, 0);
            }
        }

        // p = exp2(s*c1 - c2); mask; pack 4 key-contiguous bf16 -> one b64 write
        const bool dg = (kt == qt);
        #pragma unroll
        for (int j = 0; j < 4; ++j) {
            int kbase = k0 + j * 16 + quad * 4;
            ushortx4 pk;
            #pragma unroll
            for (int r = 0; r < 4; ++r) {
                float p = exp2f(sa[j][r] * c1 - c2);
                if (dg && (kbase + r) > qrow) p = 0.0f;
                lsum += p;
                pk[r] = f2bf(p);
            }
            *(ushortx4*)&QPs[(w * 16 + lm) * LD + j * 16 + quad * 4] = pk;
        }

        // O += P V: A = P (m=q, k=key) read back from own strip; B = V^T
        #pragma unroll
        for (int kk = 0; kk < 2; ++kk) {
            bf16x8 pf = *(const bf16x8*)&QPs[(w * 16 + lm) * LD + kk * 32 + quad * 8];
            #pragma unroll
            for (int j = 0; j < 4; ++j) {
                bf16x8 vf = *(const bf16x8*)&Vs[(j * 16 + lm) * LD + kk * 32 + quad * 8];
                o[j] = __builtin_amdgcn_mfma_f32_16x16x32_bf16(pf, vf, o[j], 0, 0, 0);
            }
        }
    }

    // row-sum lives at lane lm (replicated over quads after reduce);
    // redistribute to C-layout rows quad*4+r for the epilogue division.
    float lt = lsum;
    lt += __shfl_xor(lt, 16, 64);
    lt += __shfl_xor(lt, 32, 64);
    float rv = 1.0f / lt;
    float rinv[4];
    #pragma unroll
    for (int r = 0; r < 4; ++r)
        rinv[r] = __shfl(rv, (quad << 4) + quad * 4 + r, 64);

    #pragma unroll
    for (int j = 0; j < 4; ++j) {
        int colg = h * 64 + j * 16 + lm;
        #pragma unroll
        for (int r = 0; r < 4; ++r) {
            int rowg = q0 + w * 16 + quad * 4 + r;
            Y[((size_t)(b * 2048 + rowg)) * 1024 + colg] = f2bf(o[j][r] * rinv[r]);
        }
    }
}

// ---------------------------------------------------------------------------
extern "C" void kernel_launch(void* const* d_in, const int* in_sizes, int n_in,
                              void* d_out, int out_size, void* d_ws, size_t ws_size,
                              hipStream_t stream)
{
    const float* x      = (const float*)d_in[0];   // [2,2048,1024] fp32
    const float* w_attn = (const float*)d_in[1];   // [3072,1024] fp32
    const float* w_proj = (const float*)d_in[2];   // [1024,1024] fp32
    float* out = (float*)d_out;                    // [2,2048,1024] fp32

    // ws: qk 16.8MB | Vt 8.4MB | y 8.4MB | wpb 2.1MB  (35.7 MB total)
    unsigned short* qkbuf = (unsigned short*)d_ws;
    unsigned short* Vtb   = qkbuf + (size_t)4096 * 2048;
    unsigned short* y     = Vtb   + (size_t)32 * 64 * 2048;
    unsigned short* wpb   = y     + (size_t)4096 * 1024;
    // d_out doubles as pre-cast scratch for xb/wab (dead before proj writes):
    unsigned short* xb  = (unsigned short*)d_out;             // 8.4MB
    unsigned short* wab = xb + (size_t)4096 * 1024;           // 6.3MB

    dim3 blk(256);
    cast_inputs<<<dim3(1024), blk, 0, stream>>>(x, w_attn, w_proj, xb, wab, wpb);
    gemm_bt<true>
        <<<dim3(24, 32), blk, 0, stream>>>(xb, wab, qkbuf, nullptr, Vtb, 4096, 3072, 1024);
    rmsnorm_rope<<<dim3(16384), blk, 0, stream>>>(qkbuf);
    attention<<<dim3(32, 32), blk, 0, stream>>>(qkbuf, Vtb, y);
    gemm_bt<false>
        <<<dim3(8, 32), blk, 0, stream>>>(y, wpb, nullptr, out, nullptr, 4096, 1024, 1024);
}